// Round 5
// baseline (236.900 us; speedup 1.0000x reference)
//
#include <hip/hip_runtime.h>
#include <hip/hip_bf16.h>
#include <math.h>

#define NB 32
#define NS 1024
#define NH 512
#define NE 1024   // 2H
#define NEGV -1e10f

typedef _Float16 f16x8 __attribute__((ext_vector_type(8)));
typedef float f32x4 __attribute__((ext_vector_type(4)));

// c[b][h] = b_attn[h] + sum_e hidden[b][e] * W_h[e][h]   (fp32, tiny)
__global__ __launch_bounds__(256) void proj_h_kernel(
    const float* __restrict__ hidden, const float* __restrict__ W_attn,
    const float* __restrict__ b_attn, float* __restrict__ c) {
  int b = blockIdx.x >> 1;
  int h = ((blockIdx.x & 1) << 8) + threadIdx.x;
  __shared__ float hid[NH];
  for (int e = threadIdx.x; e < NH; e += 256) hid[e] = hidden[b * NH + e];
  __syncthreads();
  float acc = b_attn[h];
#pragma unroll 8
  for (int e = 0; e < NH; ++e) acc = fmaf(hid[e], W_attn[(size_t)e * NH + h], acc);
  c[b * NH + h] = acc;
}

// WeT[col][k] = fp16(W_e[k][col]) — transposed so B k-runs are contiguous.
__global__ __launch_bounds__(256) void prep_We_kernel(
    const float* __restrict__ W_attn, _Float16* __restrict__ WeT) {
  int k = blockIdx.x;  // 0..1023
  const float* src = W_attn + (size_t)(NH + k) * NH;
#pragma unroll
  for (int j = 0; j < 2; ++j) {
    int col = threadIdx.x + (j << 8);
    WeT[(size_t)col * NE + k] = (_Float16)src[col];
  }
}

// Fused  tanh(enc@W_e + c) . W_v  partials over a 256-col chunk.
// NO LDS, NO barriers: A (16 KB/kt tile, L1) and B (512 KB chunk, L2) fragments
// loaded straight into registers; depth-1 software pipeline over 32 k-slices.
__global__ __launch_bounds__(256) void score_kernel(
    const float* __restrict__ enc, const _Float16* __restrict__ WeT,
    const float* __restrict__ c, const float* __restrict__ Wv,
    float* __restrict__ spart) {
  const int tid = threadIdx.x;
  const int lane = tid & 63;
  const int wid = tid >> 6;                    // wave = N-position (4 x 64 cols)
  const int bx = blockIdx.x;                   // 512 M-tiles
  const int lb = ((bx & 7) << 6) + (bx >> 3);  // bijective XCD swizzle (512%8==0)
  const int b = lb >> 4;
  const int s0 = (lb & 15) << 6;
  const int nc = blockIdx.y;                   // 0..1 column chunk of 256
  const int r15 = lane & 15;
  const int khi = (lane >> 4) << 3;            // k-subgroup offset 0/8/16/24

  const float* encb = enc + ((size_t)b * NS + s0) * NE;
  const _Float16* WB = WeT + ((size_t)(nc << 8)) * NE;

  // per-lane fragment base pointers (row/col fixed, k advances)
  const float* aptr[4];
#pragma unroll
  for (int mi = 0; mi < 4; ++mi) aptr[mi] = encb + (size_t)((mi << 4) + r15) * NE + khi;
  const _Float16* bptr[4];
#pragma unroll
  for (int nj = 0; nj < 4; ++nj)
    bptr[nj] = WB + (size_t)((wid << 6) + (nj << 4) + r15) * NE + khi;

  f32x4 acc[4][4];
#pragma unroll
  for (int i = 0; i < 4; ++i)
#pragma unroll
    for (int j = 0; j < 4; ++j) acc[i][j] = (f32x4)0.f;

  f16x8 af[2][4], bf[2][4];

#define LOADF(S, KS)                                                            \
  {                                                                             \
    const int ko = (KS) << 5;                                                   \
    _Pragma("unroll") for (int mi = 0; mi < 4; ++mi) {                          \
      float4 u = *(const float4*)(aptr[mi] + ko);                               \
      float4 v = *(const float4*)(aptr[mi] + ko + 4);                           \
      f16x8 h;                                                                  \
      h[0] = (_Float16)u.x; h[1] = (_Float16)u.y;                               \
      h[2] = (_Float16)u.z; h[3] = (_Float16)u.w;                               \
      h[4] = (_Float16)v.x; h[5] = (_Float16)v.y;                               \
      h[6] = (_Float16)v.z; h[7] = (_Float16)v.w;                               \
      af[S][mi] = h;                                                            \
    }                                                                           \
    _Pragma("unroll") for (int nj = 0; nj < 4; ++nj)                            \
        bf[S][nj] = *(const f16x8*)(bptr[nj] + ko);                             \
  }

#define MFMAF(S)                                                                \
  _Pragma("unroll") for (int mi = 0; mi < 4; ++mi)                              \
      _Pragma("unroll") for (int nj = 0; nj < 4; ++nj)                          \
          acc[mi][nj] = __builtin_amdgcn_mfma_f32_16x16x32_f16(                 \
              af[S][mi], bf[S][nj], acc[mi][nj], 0, 0, 0);

  // 32 k-slices of 32; load slice ks+1 while MFMAing slice ks (no barriers,
  // so these overlap freely across iterations too).
  LOADF(0, 0);
  for (int kt = 0; kt < 16; ++kt) {
    const int ks = kt << 1;
    LOADF(1, ks + 1);
    MFMAF(0);
    if (ks + 2 < 32) LOADF(0, ks + 2);
    MFMAF(1);
  }
#undef LOADF
#undef MFMAF

  // ---- epilogue: tanh + W_v dot over this wave's 64 cols ----
  float sr[4][4];
#pragma unroll
  for (int i = 0; i < 4; ++i)
#pragma unroll
    for (int r = 0; r < 4; ++r) sr[i][r] = 0.f;
#pragma unroll
  for (int nj = 0; nj < 4; ++nj) {
    int hcol = (nc << 8) + (wid << 6) + (nj << 4) + r15;
    float wvj = Wv[hcol];
    float cvj = c[b * NH + hcol];
#pragma unroll
    for (int mi = 0; mi < 4; ++mi)
#pragma unroll
      for (int r = 0; r < 4; ++r)
        sr[mi][r] += wvj * tanhf(acc[mi][nj][r] + cvj);
  }
  // reduce across the 16 col-lanes (fixed order -> deterministic)
#pragma unroll
  for (int off = 1; off < 16; off <<= 1)
#pragma unroll
    for (int mi = 0; mi < 4; ++mi)
#pragma unroll
      for (int r = 0; r < 4; ++r) sr[mi][r] += __shfl_xor(sr[mi][r], off, 64);
  if (r15 == 0) {
    float* dst = spart + (size_t)((nc << 2) + wid) * NB * NS + b * NS + s0;
#pragma unroll
    for (int mi = 0; mi < 4; ++mi)
#pragma unroll
      for (int r = 0; r < 4; ++r)
        dst[(mi << 4) + ((lane >> 4) << 2) + r] = sr[mi][r];
  }
}

// masked softmax over S per batch row; sums the 8 score partials first
__global__ __launch_bounds__(256) void softmax_kernel(
    const float* __restrict__ spart, const int* __restrict__ mask,
    float* __restrict__ attn) {
  int b = blockIdx.x, tid = threadIdx.x;
  __shared__ float red[8];
  float v[4];
  float mx = -INFINITY;
#pragma unroll
  for (int j = 0; j < 4; ++j) {
    int s = tid + (j << 8);
    float x = 0.f;
#pragma unroll
    for (int p = 0; p < 8; ++p) x += spart[(size_t)p * NB * NS + b * NS + s];
    v[j] = (mask[b * NS + s] == 0) ? NEGV : x;
    mx = fmaxf(mx, v[j]);
  }
#pragma unroll
  for (int off = 32; off >= 1; off >>= 1) mx = fmaxf(mx, __shfl_xor(mx, off, 64));
  if ((tid & 63) == 0) red[tid >> 6] = mx;
  __syncthreads();
  mx = fmaxf(fmaxf(red[0], red[1]), fmaxf(red[2], red[3]));
  float sum = 0.f;
#pragma unroll
  for (int j = 0; j < 4; ++j) {
    v[j] = __expf(v[j] - mx);
    sum += v[j];
  }
#pragma unroll
  for (int off = 32; off >= 1; off >>= 1) sum += __shfl_xor(sum, off, 64);
  __syncthreads();
  if ((tid & 63) == 0) red[4 + (tid >> 6)] = sum;
  __syncthreads();
  float inv = 1.f / (red[4] + red[5] + red[6] + red[7]);
#pragma unroll
  for (int j = 0; j < 4; ++j) attn[b * NS + tid + (j << 8)] = v[j] * inv;
}

// partial context over a 64-row S chunk
__global__ __launch_bounds__(256) void ctx_partial_kernel(
    const float* __restrict__ enc, const float* __restrict__ attn,
    float* __restrict__ partial) {
  int ch = blockIdx.x;  // 0..15
  int b = blockIdx.y;
  int tid = threadIdx.x;
  __shared__ float w[64];
  if (tid < 64) w[tid] = attn[b * NS + (ch << 6) + tid];
  __syncthreads();
  const float* encb = enc + ((size_t)b * NS + (ch << 6)) * NE;
  float4 acc = make_float4(0.f, 0.f, 0.f, 0.f);
  int e = tid << 2;
  for (int s = 0; s < 64; ++s) {
    float4 x = *(const float4*)(encb + (size_t)s * NE + e);
    float ws_ = w[s];
    acc.x = fmaf(ws_, x.x, acc.x);
    acc.y = fmaf(ws_, x.y, acc.y);
    acc.z = fmaf(ws_, x.z, acc.z);
    acc.w = fmaf(ws_, x.w, acc.w);
  }
  *(float4*)(partial + ((size_t)(b * 16 + ch)) * NE + e) = acc;
}

__global__ __launch_bounds__(256) void ctx_reduce_kernel(
    const float* __restrict__ partial, float* __restrict__ ctx) {
  int b = blockIdx.x;
  int e = threadIdx.x << 2;
  float4 acc = make_float4(0.f, 0.f, 0.f, 0.f);
  for (int ch = 0; ch < 16; ++ch) {
    float4 x = *(const float4*)(partial + ((size_t)(b * 16 + ch)) * NE + e);
    acc.x += x.x;
    acc.y += x.y;
    acc.z += x.z;
    acc.w += x.w;
  }
  *(float4*)(ctx + (size_t)b * NE + e) = acc;
}

extern "C" void kernel_launch(void* const* d_in, const int* in_sizes, int n_in,
                              void* d_out, int out_size, void* d_ws, size_t ws_size,
                              hipStream_t stream) {
  const float* hidden = (const float*)d_in[0];
  const float* enc = (const float*)d_in[1];
  const int* mask = (const int*)d_in[2];
  const float* W_attn = (const float*)d_in[3];
  const float* b_attn = (const float*)d_in[4];
  const float* W_v = (const float*)d_in[5];

  float* ctx = (float*)d_out;   // context: 32*1024
  float* attn = ctx + NB * NS;  // attn_w: 32*1024

  float* ws = (float*)d_ws;
  float* c = ws;                                       // 32*512 f32
  _Float16* WeT = (_Float16*)(ws + NB * NH);           // 512*1024 fp16 (1 MB)
  float* spart = (float*)((char*)WeT + (size_t)NH * NE * 2);  // 8*32*1024 f32
  float* partial = spart + 8 * NB * NS;                // 32*16*1024 f32

  proj_h_kernel<<<64, 256, 0, stream>>>(hidden, W_attn, b_attn, c);
  prep_We_kernel<<<NE, 256, 0, stream>>>(W_attn, WeT);
  score_kernel<<<dim3(512, 2), 256, 0, stream>>>(enc, WeT, c, W_v, spart);
  softmax_kernel<<<NB, 256, 0, stream>>>(spart, mask, attn);
  ctx_partial_kernel<<<dim3(16, NB), 256, 0, stream>>>(enc, attn, partial);
  ctx_reduce_kernel<<<NB, 256, 0, stream>>>(partial, ctx);
}

// Round 6
// 197.941 us; speedup vs baseline: 1.1968x; 1.1968x over previous
//
#include <hip/hip_runtime.h>
#include <hip/hip_bf16.h>
#include <math.h>

#define NB 32
#define NS 1024
#define NH 512
#define NE 1024   // 2H
#define NEGV -1e10f

typedef _Float16 f16x8 __attribute__((ext_vector_type(8)));
typedef _Float16 f16x4 __attribute__((ext_vector_type(4)));
typedef float f32x4 __attribute__((ext_vector_type(4)));

// c[b][h] = b_attn[h] + sum_e hidden[b][e] * W_h[e][h]   (fp32, tiny)
__global__ __launch_bounds__(256) void proj_h_kernel(
    const float* __restrict__ hidden, const float* __restrict__ W_attn,
    const float* __restrict__ b_attn, float* __restrict__ c) {
  int b = blockIdx.x >> 1;
  int h = ((blockIdx.x & 1) << 8) + threadIdx.x;
  __shared__ float hid[NH];
  for (int e = threadIdx.x; e < NH; e += 256) hid[e] = hidden[b * NH + e];
  __syncthreads();
  float acc = b_attn[h];
#pragma unroll 8
  for (int e = 0; e < NH; ++e) acc = fmaf(hid[e], W_attn[(size_t)e * NH + h], acc);
  c[b * NH + h] = acc;
}

// WeT[col][k] = fp16(W_e[k][col]) — transposed so B k-runs are contiguous.
__global__ __launch_bounds__(256) void prep_We_kernel(
    const float* __restrict__ W_attn, _Float16* __restrict__ WeT) {
  int k = blockIdx.x;  // 0..1023
  const float* src = W_attn + (size_t)(NH + k) * NH;
#pragma unroll
  for (int j = 0; j < 2; ++j) {
    int col = threadIdx.x + (j << 8);
    WeT[(size_t)col * NE + k] = (_Float16)src[col];
  }
}

// Fused  tanh(enc@W_e + c) . W_v  over ALL 512 cols per block.
// M-tile=32, K=1024: whole A-panel staged ONCE to 64 KB swizzled LDS
// (single barrier), then a BARRIER-FREE K-loop: A-frags from LDS (~120cy),
// B-frags from L2-resident WeT (1 MB), 16 MFMA per k-slice. No HBM and no
// barrier on the K-loop critical path -> compiler can pipeline slices.
__global__ __launch_bounds__(256) void score_kernel(
    const float* __restrict__ enc, const _Float16* __restrict__ WeT,
    const float* __restrict__ c, const float* __restrict__ Wv,
    float* __restrict__ spart) {
  __shared__ _Float16 Asm[32 * 1024];  // 64 KB, [row][k] swizzled
  const int tid = threadIdx.x;
  const int lane = tid & 63;
  const int wid = tid >> 6;                     // wave covers cols wid*128..+127
  const int bx = blockIdx.x;                    // 1024 M-tiles
  const int lb = ((bx & 7) << 7) + (bx >> 3);   // bijective XCD swizzle (1024%8==0)
  const int b = lb >> 5;
  const int s0 = (lb & 31) << 5;
  const int r15 = lane & 15;
  const int khi = (lane >> 4) << 3;             // k-subgroup float16 offset 0/8/16/24

  const float* encb = enc + ((size_t)b * NS + s0) * NE;

  // ---- stage A once: 32 rows x 1024 k, fp32 -> fp16, swizzled ----
  // thread pass q handles row q, float4 index tid (coalesced 1 KB/wave).
#pragma unroll 8
  for (int q = 0; q < 32; ++q) {
    float4 v = *(const float4*)(encb + (size_t)q * NE + (tid << 2));
    f16x4 h;
    h[0] = (_Float16)v.x; h[1] = (_Float16)v.y;
    h[2] = (_Float16)v.z; h[3] = (_Float16)v.w;
    int off = (q << 11) + (tid << 3);
    off ^= (q & 7) << 4;
    *(f16x4*)((char*)Asm + off) = h;
  }
  __syncthreads();

  // per-lane B pointers: col = wid*128 + nj*16 + r15, k advances
  const _Float16* bptr[8];
#pragma unroll
  for (int nj = 0; nj < 8; ++nj)
    bptr[nj] = WeT + (size_t)((wid << 7) + (nj << 4) + r15) * NE + khi;

  f32x4 acc[2][8];
#pragma unroll
  for (int i = 0; i < 2; ++i)
#pragma unroll
    for (int j = 0; j < 8; ++j) acc[i][j] = (f32x4)0.f;

  // ---- barrier-free K-loop: 32 k-slices of 32 ----
#pragma unroll 4
  for (int ks = 0; ks < 32; ++ks) {
    f16x8 af[2], bf[8];
#pragma unroll
    for (int mi = 0; mi < 2; ++mi) {
      int row = (mi << 4) + r15;
      int off = (row << 11) + (ks << 6) + ((lane >> 4) << 4);
      off ^= (row & 7) << 4;
      af[mi] = *(const f16x8*)((const char*)Asm + off);
    }
#pragma unroll
    for (int nj = 0; nj < 8; ++nj) bf[nj] = *(const f16x8*)(bptr[nj] + (ks << 5));
#pragma unroll
    for (int mi = 0; mi < 2; ++mi)
#pragma unroll
      for (int nj = 0; nj < 8; ++nj)
        acc[mi][nj] = __builtin_amdgcn_mfma_f32_16x16x32_f16(af[mi], bf[nj], acc[mi][nj], 0, 0, 0);
  }

  // ---- epilogue: tanh + W_v dot over this wave's 128 cols ----
  float sr[2][4];
#pragma unroll
  for (int i = 0; i < 2; ++i)
#pragma unroll
    for (int r = 0; r < 4; ++r) sr[i][r] = 0.f;
#pragma unroll
  for (int nj = 0; nj < 8; ++nj) {
    int hcol = (wid << 7) + (nj << 4) + r15;
    float wvj = Wv[hcol];
    float cvj = c[b * NH + hcol];
#pragma unroll
    for (int mi = 0; mi < 2; ++mi)
#pragma unroll
      for (int r = 0; r < 4; ++r)
        sr[mi][r] += wvj * tanhf(acc[mi][nj][r] + cvj);
  }
  // reduce across the 16 col-lanes (fixed order -> deterministic)
#pragma unroll
  for (int off = 1; off < 16; off <<= 1)
#pragma unroll
    for (int mi = 0; mi < 2; ++mi)
#pragma unroll
      for (int r = 0; r < 4; ++r) sr[mi][r] += __shfl_xor(sr[mi][r], off, 64);
  if (r15 == 0) {
    float* dst = spart + (size_t)wid * NB * NS + b * NS + s0;
#pragma unroll
    for (int mi = 0; mi < 2; ++mi)
#pragma unroll
      for (int r = 0; r < 4; ++r)
        dst[(mi << 4) + ((lane >> 4) << 2) + r] = sr[mi][r];
  }
}

// masked softmax over S per batch row; sums the 4 score partials first
__global__ __launch_bounds__(256) void softmax_kernel(
    const float* __restrict__ spart, const int* __restrict__ mask,
    float* __restrict__ attn) {
  int b = blockIdx.x, tid = threadIdx.x;
  __shared__ float red[8];
  float v[4];
  float mx = -INFINITY;
#pragma unroll
  for (int j = 0; j < 4; ++j) {
    int s = tid + (j << 8);
    float x = 0.f;
#pragma unroll
    for (int p = 0; p < 4; ++p) x += spart[(size_t)p * NB * NS + b * NS + s];
    v[j] = (mask[b * NS + s] == 0) ? NEGV : x;
    mx = fmaxf(mx, v[j]);
  }
#pragma unroll
  for (int off = 32; off >= 1; off >>= 1) mx = fmaxf(mx, __shfl_xor(mx, off, 64));
  if ((tid & 63) == 0) red[tid >> 6] = mx;
  __syncthreads();
  mx = fmaxf(fmaxf(red[0], red[1]), fmaxf(red[2], red[3]));
  float sum = 0.f;
#pragma unroll
  for (int j = 0; j < 4; ++j) {
    v[j] = __expf(v[j] - mx);
    sum += v[j];
  }
#pragma unroll
  for (int off = 32; off >= 1; off >>= 1) sum += __shfl_xor(sum, off, 64);
  __syncthreads();
  if ((tid & 63) == 0) red[4 + (tid >> 6)] = sum;
  __syncthreads();
  float inv = 1.f / (red[4] + red[5] + red[6] + red[7]);
#pragma unroll
  for (int j = 0; j < 4; ++j) attn[b * NS + tid + (j << 8)] = v[j] * inv;
}

// partial context over a 64-row S chunk
__global__ __launch_bounds__(256) void ctx_partial_kernel(
    const float* __restrict__ enc, const float* __restrict__ attn,
    float* __restrict__ partial) {
  int ch = blockIdx.x;  // 0..15
  int b = blockIdx.y;
  int tid = threadIdx.x;
  __shared__ float w[64];
  if (tid < 64) w[tid] = attn[b * NS + (ch << 6) + tid];
  __syncthreads();
  const float* encb = enc + ((size_t)b * NS + (ch << 6)) * NE;
  float4 acc = make_float4(0.f, 0.f, 0.f, 0.f);
  int e = tid << 2;
  for (int s = 0; s < 64; ++s) {
    float4 x = *(const float4*)(encb + (size_t)s * NE + e);
    float ws_ = w[s];
    acc.x = fmaf(ws_, x.x, acc.x);
    acc.y = fmaf(ws_, x.y, acc.y);
    acc.z = fmaf(ws_, x.z, acc.z);
    acc.w = fmaf(ws_, x.w, acc.w);
  }
  *(float4*)(partial + ((size_t)(b * 16 + ch)) * NE + e) = acc;
}

__global__ __launch_bounds__(256) void ctx_reduce_kernel(
    const float* __restrict__ partial, float* __restrict__ ctx) {
  int b = blockIdx.x;
  int e = threadIdx.x << 2;
  float4 acc = make_float4(0.f, 0.f, 0.f, 0.f);
  for (int ch = 0; ch < 16; ++ch) {
    float4 x = *(const float4*)(partial + ((size_t)(b * 16 + ch)) * NE + e);
    acc.x += x.x;
    acc.y += x.y;
    acc.z += x.z;
    acc.w += x.w;
  }
  *(float4*)(ctx + (size_t)b * NE + e) = acc;
}

extern "C" void kernel_launch(void* const* d_in, const int* in_sizes, int n_in,
                              void* d_out, int out_size, void* d_ws, size_t ws_size,
                              hipStream_t stream) {
  const float* hidden = (const float*)d_in[0];
  const float* enc = (const float*)d_in[1];
  const int* mask = (const int*)d_in[2];
  const float* W_attn = (const float*)d_in[3];
  const float* b_attn = (const float*)d_in[4];
  const float* W_v = (const float*)d_in[5];

  float* ctx = (float*)d_out;   // context: 32*1024
  float* attn = ctx + NB * NS;  // attn_w: 32*1024

  float* ws = (float*)d_ws;
  float* c = ws;                                       // 32*512 f32
  _Float16* WeT = (_Float16*)(ws + NB * NH);           // 512*1024 fp16 (1 MB)
  float* spart = (float*)((char*)WeT + (size_t)NH * NE * 2);  // 4*32*1024 f32
  float* partial = spart + 4 * NB * NS;                // 32*16*1024 f32

  proj_h_kernel<<<64, 256, 0, stream>>>(hidden, W_attn, b_attn, c);
  prep_We_kernel<<<NE, 256, 0, stream>>>(W_attn, WeT);
  score_kernel<<<1024, 256, 0, stream>>>(enc, WeT, c, W_v, spart);
  softmax_kernel<<<NB, 256, 0, stream>>>(spart, mask, attn);
  ctx_partial_kernel<<<dim3(16, NB), 256, 0, stream>>>(enc, attn, partial);
  ctx_reduce_kernel<<<NB, 256, 0, stream>>>(partial, ctx);
}

// Round 7
// 146.676 us; speedup vs baseline: 1.6151x; 1.3495x over previous
//
#include <hip/hip_runtime.h>
#include <hip/hip_bf16.h>
#include <math.h>

#define NB 32
#define NS 1024
#define NH 512
#define NE 1024   // 2H
#define NEGV -1e10f

typedef _Float16 f16x8 __attribute__((ext_vector_type(8)));
typedef _Float16 f16x4 __attribute__((ext_vector_type(4)));
typedef float f32x4 __attribute__((ext_vector_type(4)));

// c[b][h] = b_attn[h] + sum_e hidden[b][e] * W_h[e][h]   (fp32, tiny)
__global__ __launch_bounds__(256) void proj_h_kernel(
    const float* __restrict__ hidden, const float* __restrict__ W_attn,
    const float* __restrict__ b_attn, float* __restrict__ c) {
  int b = blockIdx.x >> 1;
  int h = ((blockIdx.x & 1) << 8) + threadIdx.x;
  __shared__ float hid[NH];
  for (int e = threadIdx.x; e < NH; e += 256) hid[e] = hidden[b * NH + e];
  __syncthreads();
  float acc = b_attn[h];
#pragma unroll 8
  for (int e = 0; e < NH; ++e) acc = fmaf(hid[e], W_attn[(size_t)e * NH + h], acc);
  c[b * NH + h] = acc;
}

// WeT[col][k] = fp16(W_e[k][col]) — transposed so B k-runs are contiguous.
__global__ __launch_bounds__(256) void prep_We_kernel(
    const float* __restrict__ W_attn, _Float16* __restrict__ WeT) {
  int k = blockIdx.x;  // 0..1023
  const float* src = W_attn + (size_t)(NH + k) * NH;
#pragma unroll
  for (int j = 0; j < 2; ++j) {
    int col = threadIdx.x + (j << 8);
    WeT[(size_t)col * NE + k] = (_Float16)src[col];
  }
}

// enc fp32 -> fp16, memory-bound grid-stride pass (also warms L3 with enc).
__global__ __launch_bounds__(256) void prep_enc_kernel(
    const float* __restrict__ enc, _Float16* __restrict__ encf) {
  const size_t n4 = (size_t)NB * NS * NE / 4;  // 8388608 float4s
  const size_t stride = (size_t)gridDim.x * 256;
  for (size_t i = (size_t)blockIdx.x * 256 + threadIdx.x; i < n4; i += stride) {
    float4 v = *(const float4*)(enc + i * 4);
    f16x4 h;
    h[0] = (_Float16)v.x; h[1] = (_Float16)v.y;
    h[2] = (_Float16)v.z; h[3] = (_Float16)v.w;
    *(f16x4*)(encf + i * 4) = h;
  }
}

// Fused  tanh(enc@W_e + c) . W_v  partials over a 256-col chunk.
// Tile 64(M)x256(N), BK=64, 4 waves (wave tile 64x64, acc 4x4).
// Pure global_load_lds staging for A (encf16) AND B (WeT), pre-swizzled src,
// double-buffered LDS. One barrier per K-step: STAGE(t+1) issued BEFORE
// compute(t), so the barrier's vmcnt(0) drain lands after compute covered
// the load latency (T3 minimum-2-phase recipe).
__global__ __launch_bounds__(256) void score_kernel(
    const _Float16* __restrict__ encf, const _Float16* __restrict__ WeT,
    const float* __restrict__ c, const float* __restrict__ Wv,
    float* __restrict__ spart) {
  __shared__ _Float16 Asm[2][64 * 64];    // 8 KB each, [row][k] swizzled
  __shared__ _Float16 Bsm[2][256 * 64];   // 32 KB each, [col][k] swizzled
  const int tid = threadIdx.x;
  const int lane = tid & 63;
  const int wid = tid >> 6;                    // wave = N-position
  const int bx = blockIdx.x;                   // 512 M-tiles
  const int lb = ((bx & 7) << 6) + (bx >> 3);  // bijective XCD swizzle (512%8==0)
  const int b = lb >> 4;
  const int s0 = (lb & 15) << 6;
  const int nc = blockIdx.y;                   // 0..1 column chunk of 256
  const int r15 = lane & 15;
  const char* encbase = (const char*)(encf + ((size_t)b * NS + s0) * NE);
  const char* Wbytes = (const char*)(WeT + ((size_t)(nc << 8)) * NE);

  f32x4 acc[4][4];
#pragma unroll
  for (int i = 0; i < 4; ++i)
#pragma unroll
    for (int j = 0; j < 4; ++j) acc[i][j] = (f32x4)0.f;

  // LDS content at byte d equals linear src byte (d&~127)|((d&127)^((r&7)<<4))
  // (rule #21: linear dest + inverse-swizzled source + swizzled read).
#define STAGE(KT, BUF)                                                          \
  {                                                                             \
    const char* Akt = encbase + ((KT) << 7);                                    \
    _Pragma("unroll") for (int i = 0; i < 2; ++i) {                             \
      int dbase = (wid << 11) + (i << 10);                                      \
      int d = dbase + (lane << 4);                                              \
      int row = d >> 7;                                                         \
      int sb = (d & 127) ^ ((row & 7) << 4);                                    \
      __builtin_amdgcn_global_load_lds(                                         \
          (const __attribute__((address_space(1))) uint32_t*)(Akt + (size_t)row * (NE * 2) + sb), \
          (__attribute__((address_space(3))) uint32_t*)((char*)Asm[BUF] + dbase),\
          16, 0, 0);                                                            \
    }                                                                           \
    const char* Bkt = Wbytes + ((KT) << 7);                                     \
    _Pragma("unroll") for (int i = 0; i < 8; ++i) {                             \
      int dbase = (wid << 13) + (i << 10);                                      \
      int d = dbase + (lane << 4);                                              \
      int col = d >> 7;                                                         \
      int sb = (d & 127) ^ ((col & 7) << 4);                                    \
      __builtin_amdgcn_global_load_lds(                                         \
          (const __attribute__((address_space(1))) uint32_t*)(Bkt + (size_t)col * (NE * 2) + sb), \
          (__attribute__((address_space(3))) uint32_t*)((char*)Bsm[BUF] + dbase),\
          16, 0, 0);                                                            \
    }                                                                           \
  }

  STAGE(0, 0);
  __syncthreads();

  for (int kt = 0; kt < 16; ++kt) {
    const int cur = kt & 1, nxt = cur ^ 1;
    if (kt < 15) STAGE(kt + 1, nxt);   // issue-before-compute: latency hides
    // ---- compute on LDS[cur]: 2 k-slices of 32 ----
#pragma unroll
    for (int kk = 0; kk < 2; ++kk) {
      f16x8 af[4], bf[4];
#pragma unroll
      for (int mi = 0; mi < 4; ++mi) {
        int row = (mi << 4) + r15;
        int off = (row << 7) + (kk << 6) + ((lane >> 4) << 4);
        off ^= (row & 7) << 4;
        af[mi] = *(const f16x8*)((const char*)Asm[cur] + off);
      }
#pragma unroll
      for (int nj = 0; nj < 4; ++nj) {
        int cb = (wid << 6) + (nj << 4) + r15;
        int off = (cb << 7) + (kk << 6) + ((lane >> 4) << 4);
        off ^= (cb & 7) << 4;
        bf[nj] = *(const f16x8*)((const char*)Bsm[cur] + off);
      }
#pragma unroll
      for (int mi = 0; mi < 4; ++mi)
#pragma unroll
        for (int nj = 0; nj < 4; ++nj)
          acc[mi][nj] = __builtin_amdgcn_mfma_f32_16x16x32_f16(af[mi], bf[nj], acc[mi][nj], 0, 0, 0);
    }
    __syncthreads();  // drains STAGE(t+1); protects both LDS buffers
  }
#undef STAGE

  // ---- epilogue: tanh + W_v dot over this wave's 64 cols ----
  float sr[4][4];
#pragma unroll
  for (int i = 0; i < 4; ++i)
#pragma unroll
    for (int r = 0; r < 4; ++r) sr[i][r] = 0.f;
#pragma unroll
  for (int nj = 0; nj < 4; ++nj) {
    int hcol = (nc << 8) + (wid << 6) + (nj << 4) + r15;
    float wvj = Wv[hcol];
    float cvj = c[b * NH + hcol];
#pragma unroll
    for (int mi = 0; mi < 4; ++mi)
#pragma unroll
      for (int r = 0; r < 4; ++r)
        sr[mi][r] += wvj * tanhf(acc[mi][nj][r] + cvj);
  }
#pragma unroll
  for (int off = 1; off < 16; off <<= 1)
#pragma unroll
    for (int mi = 0; mi < 4; ++mi)
#pragma unroll
      for (int r = 0; r < 4; ++r) sr[mi][r] += __shfl_xor(sr[mi][r], off, 64);
  if (r15 == 0) {
    float* dst = spart + (size_t)((nc << 2) + wid) * NB * NS + b * NS + s0;
#pragma unroll
    for (int mi = 0; mi < 4; ++mi)
#pragma unroll
      for (int r = 0; r < 4; ++r)
        dst[(mi << 4) + ((lane >> 4) << 2) + r] = sr[mi][r];
  }
}

// ---- fallback score (R3 verbatim): used when ws too small for encf16 ----
__global__ __launch_bounds__(256) void score_fb_kernel(
    const float* __restrict__ enc, const _Float16* __restrict__ WeT,
    const float* __restrict__ c, const float* __restrict__ Wv,
    float* __restrict__ spart) {
  __shared__ _Float16 Asm[64 * 64];
  __shared__ _Float16 Bsm[256 * 64];
  const int tid = threadIdx.x;
  const int lane = tid & 63;
  const int wid = tid >> 6;
  const int bx = blockIdx.x;
  const int lb = ((bx & 7) << 6) + (bx >> 3);
  const int b = lb >> 4;
  const int s0 = (lb & 15) << 6;
  const int nc = blockIdx.y;
  const float* encb = enc + ((size_t)b * NS + s0) * NE;
  const char* Wbytes = (const char*)(WeT + ((size_t)(nc << 8)) * NE);

  f32x4 acc[4][4];
#pragma unroll
  for (int i = 0; i < 4; ++i)
#pragma unroll
    for (int j = 0; j < 4; ++j) acc[i][j] = (f32x4)0.f;

  for (int kt = 0; kt < 16; ++kt) {
#pragma unroll
    for (int q = 0; q < 4; ++q) {
      int f4 = (q << 8) + tid;
      int row = f4 >> 4, kq = f4 & 15;
      float4 v = *(const float4*)(encb + (size_t)row * NE + (kt << 6) + (kq << 2));
      f16x4 h;
      h[0] = (_Float16)v.x; h[1] = (_Float16)v.y;
      h[2] = (_Float16)v.z; h[3] = (_Float16)v.w;
      int off = (row << 7) + (kq << 3);
      off ^= (row & 7) << 4;
      *(f16x4*)((char*)Asm + off) = h;
    }
    {
      const char* Wkt = Wbytes + ((size_t)kt << 7);
#pragma unroll
      for (int i = 0; i < 8; ++i) {
        int dbase = (wid << 13) + (i << 10);
        int d = dbase + (lane << 4);
        int col = d >> 7;
        int sbyte = (d & 127) ^ ((col & 7) << 4);
        const char* src = Wkt + (size_t)col * (NE * 2) + sbyte;
        __builtin_amdgcn_global_load_lds(
            (const __attribute__((address_space(1))) uint32_t*)src,
            (__attribute__((address_space(3))) uint32_t*)((char*)Bsm + dbase),
            16, 0, 0);
      }
    }
    __syncthreads();
#pragma unroll
    for (int kk = 0; kk < 2; ++kk) {
      f16x8 af[4], bf[4];
#pragma unroll
      for (int mi = 0; mi < 4; ++mi) {
        int row = (mi << 4) + (lane & 15);
        int off = (row << 7) + (kk << 6) + ((lane >> 4) << 4);
        off ^= (row & 7) << 4;
        af[mi] = *(const f16x8*)((const char*)Asm + off);
      }
#pragma unroll
      for (int nj = 0; nj < 4; ++nj) {
        int cb = (wid << 6) + (nj << 4) + (lane & 15);
        int off = (cb << 7) + (kk << 6) + ((lane >> 4) << 4);
        off ^= (cb & 7) << 4;
        bf[nj] = *(const f16x8*)((const char*)Bsm + off);
      }
#pragma unroll
      for (int mi = 0; mi < 4; ++mi)
#pragma unroll
        for (int nj = 0; nj < 4; ++nj)
          acc[mi][nj] = __builtin_amdgcn_mfma_f32_16x16x32_f16(af[mi], bf[nj], acc[mi][nj], 0, 0, 0);
    }
    __syncthreads();
  }

  float sr[4][4];
#pragma unroll
  for (int i = 0; i < 4; ++i)
#pragma unroll
    for (int r = 0; r < 4; ++r) sr[i][r] = 0.f;
#pragma unroll
  for (int nj = 0; nj < 4; ++nj) {
    int hcol = (nc << 8) + (wid << 6) + (nj << 4) + (lane & 15);
    float wvj = Wv[hcol];
    float cvj = c[b * NH + hcol];
#pragma unroll
    for (int mi = 0; mi < 4; ++mi)
#pragma unroll
      for (int r = 0; r < 4; ++r)
        sr[mi][r] += wvj * tanhf(acc[mi][nj][r] + cvj);
  }
#pragma unroll
  for (int off = 1; off < 16; off <<= 1)
#pragma unroll
    for (int mi = 0; mi < 4; ++mi)
#pragma unroll
      for (int r = 0; r < 4; ++r) sr[mi][r] += __shfl_xor(sr[mi][r], off, 64);
  if ((lane & 15) == 0) {
    float* dst = spart + (size_t)((nc << 2) + wid) * NB * NS + b * NS + s0;
#pragma unroll
    for (int mi = 0; mi < 4; ++mi)
#pragma unroll
      for (int r = 0; r < 4; ++r)
        dst[(mi << 4) + ((lane >> 4) << 2) + r] = sr[mi][r];
  }
}

// masked softmax over S per batch row; sums the 8 score partials first
__global__ __launch_bounds__(256) void softmax_kernel(
    const float* __restrict__ spart, const int* __restrict__ mask,
    float* __restrict__ attn) {
  int b = blockIdx.x, tid = threadIdx.x;
  __shared__ float red[8];
  float v[4];
  float mx = -INFINITY;
#pragma unroll
  for (int j = 0; j < 4; ++j) {
    int s = tid + (j << 8);
    float x = 0.f;
#pragma unroll
    for (int p = 0; p < 8; ++p) x += spart[(size_t)p * NB * NS + b * NS + s];
    v[j] = (mask[b * NS + s] == 0) ? NEGV : x;
    mx = fmaxf(mx, v[j]);
  }
#pragma unroll
  for (int off = 32; off >= 1; off >>= 1) mx = fmaxf(mx, __shfl_xor(mx, off, 64));
  if ((tid & 63) == 0) red[tid >> 6] = mx;
  __syncthreads();
  mx = fmaxf(fmaxf(red[0], red[1]), fmaxf(red[2], red[3]));
  float sum = 0.f;
#pragma unroll
  for (int j = 0; j < 4; ++j) {
    v[j] = __expf(v[j] - mx);
    sum += v[j];
  }
#pragma unroll
  for (int off = 32; off >= 1; off >>= 1) sum += __shfl_xor(sum, off, 64);
  __syncthreads();
  if ((tid & 63) == 0) red[4 + (tid >> 6)] = sum;
  __syncthreads();
  float inv = 1.f / (red[4] + red[5] + red[6] + red[7]);
#pragma unroll
  for (int j = 0; j < 4; ++j) attn[b * NS + tid + (j << 8)] = v[j] * inv;
}

// partial context over a 64-row S chunk — fp16 enc variant (primary path)
__global__ __launch_bounds__(256) void ctx_partial_f16_kernel(
    const _Float16* __restrict__ encf, const float* __restrict__ attn,
    float* __restrict__ partial) {
  int ch = blockIdx.x;
  int b = blockIdx.y;
  int tid = threadIdx.x;
  __shared__ float w[64];
  if (tid < 64) w[tid] = attn[b * NS + (ch << 6) + tid];
  __syncthreads();
  const _Float16* encb = encf + ((size_t)b * NS + (ch << 6)) * NE;
  float4 acc = make_float4(0.f, 0.f, 0.f, 0.f);
  int e = tid << 2;
  for (int s = 0; s < 64; ++s) {
    f16x4 x = *(const f16x4*)(encb + (size_t)s * NE + e);
    float ws_ = w[s];
    acc.x = fmaf(ws_, (float)x[0], acc.x);
    acc.y = fmaf(ws_, (float)x[1], acc.y);
    acc.z = fmaf(ws_, (float)x[2], acc.z);
    acc.w = fmaf(ws_, (float)x[3], acc.w);
  }
  *(float4*)(partial + ((size_t)(b * 16 + ch)) * NE + e) = acc;
}

// fp32 fallback
__global__ __launch_bounds__(256) void ctx_partial_kernel(
    const float* __restrict__ enc, const float* __restrict__ attn,
    float* __restrict__ partial) {
  int ch = blockIdx.x;
  int b = blockIdx.y;
  int tid = threadIdx.x;
  __shared__ float w[64];
  if (tid < 64) w[tid] = attn[b * NS + (ch << 6) + tid];
  __syncthreads();
  const float* encb = enc + ((size_t)b * NS + (ch << 6)) * NE;
  float4 acc = make_float4(0.f, 0.f, 0.f, 0.f);
  int e = tid << 2;
  for (int s = 0; s < 64; ++s) {
    float4 x = *(const float4*)(encb + (size_t)s * NE + e);
    float ws_ = w[s];
    acc.x = fmaf(ws_, x.x, acc.x);
    acc.y = fmaf(ws_, x.y, acc.y);
    acc.z = fmaf(ws_, x.z, acc.z);
    acc.w = fmaf(ws_, x.w, acc.w);
  }
  *(float4*)(partial + ((size_t)(b * 16 + ch)) * NE + e) = acc;
}

__global__ __launch_bounds__(256) void ctx_reduce_kernel(
    const float* __restrict__ partial, float* __restrict__ ctx) {
  int b = blockIdx.x;
  int e = threadIdx.x << 2;
  float4 acc = make_float4(0.f, 0.f, 0.f, 0.f);
  for (int ch = 0; ch < 16; ++ch) {
    float4 x = *(const float4*)(partial + ((size_t)(b * 16 + ch)) * NE + e);
    acc.x += x.x;
    acc.y += x.y;
    acc.z += x.z;
    acc.w += x.w;
  }
  *(float4*)(ctx + (size_t)b * NE + e) = acc;
}

extern "C" void kernel_launch(void* const* d_in, const int* in_sizes, int n_in,
                              void* d_out, int out_size, void* d_ws, size_t ws_size,
                              hipStream_t stream) {
  const float* hidden = (const float*)d_in[0];
  const float* enc = (const float*)d_in[1];
  const int* mask = (const int*)d_in[2];
  const float* W_attn = (const float*)d_in[3];
  const float* b_attn = (const float*)d_in[4];
  const float* W_v = (const float*)d_in[5];

  float* ctx = (float*)d_out;   // context: 32*1024
  float* attn = ctx + NB * NS;  // attn_w: 32*1024

  char* ws = (char*)d_ws;
  const size_t ofs_c = 0;                          // 32*512 f32   = 64 KB
  const size_t ofs_spart = 65536;                  // 8*32*1024 f32 = 1 MB
  const size_t ofs_partial = ofs_spart + 1048576;  // 32*16*1024 f32 = 2 MB
  const size_t ofs_WeT = ofs_partial + 2097152;    // 512*1024 f16  = 1 MB
  const size_t ofs_enc16 = ofs_WeT + 1048576;      // 32*1024*1024 f16 = 64 MB
  const size_t need = ofs_enc16 + (size_t)NB * NS * NE * 2;

  float* c = (float*)(ws + ofs_c);
  float* spart = (float*)(ws + ofs_spart);
  float* partial = (float*)(ws + ofs_partial);
  _Float16* WeT = (_Float16*)(ws + ofs_WeT);
  _Float16* encf = (_Float16*)(ws + ofs_enc16);

  const bool big = ws_size >= need;  // constant per session -> deterministic

  proj_h_kernel<<<64, 256, 0, stream>>>(hidden, W_attn, b_attn, c);
  prep_We_kernel<<<NE, 256, 0, stream>>>(W_attn, WeT);
  if (big) {
    prep_enc_kernel<<<2048, 256, 0, stream>>>(enc, encf);
    score_kernel<<<dim3(512, 2), 256, 0, stream>>>(encf, WeT, c, W_v, spart);
  } else {
    score_fb_kernel<<<dim3(512, 2), 256, 0, stream>>>(enc, WeT, c, W_v, spart);
  }
  softmax_kernel<<<NB, 256, 0, stream>>>(spart, mask, attn);
  if (big) {
    ctx_partial_f16_kernel<<<dim3(16, NB), 256, 0, stream>>>(encf, attn, partial);
  } else {
    ctx_partial_kernel<<<dim3(16, NB), 256, 0, stream>>>(enc, attn, partial);
  }
  ctx_reduce_kernel<<<NB, 256, 0, stream>>>(partial, ctx);
}

// Round 8
// 124.085 us; speedup vs baseline: 1.9092x; 1.1821x over previous
//
#include <hip/hip_runtime.h>
#include <hip/hip_bf16.h>
#include <math.h>

#define NB 32
#define NS 1024
#define NH 512
#define NE 1024   // 2H
#define NEGV -1e10f

typedef _Float16 f16x8 __attribute__((ext_vector_type(8)));
typedef _Float16 f16x4 __attribute__((ext_vector_type(4)));
typedef float f32x4 __attribute__((ext_vector_type(4)));

__device__ __forceinline__ float fast_tanh(float x) {
  // tanh(x) = (e^{2x}-1)/(e^{2x}+1); __expf = v_exp_f32 (saturates cleanly)
  float t = __expf(2.f * x);
  return (t - 1.f) * __builtin_amdgcn_rcpf(t + 1.f);
}

// c[b][h] = b_attn[h] + sum_e hidden[b][e] * W_h[e][h]   (fp32, tiny)
__global__ __launch_bounds__(256) void proj_h_kernel(
    const float* __restrict__ hidden, const float* __restrict__ W_attn,
    const float* __restrict__ b_attn, float* __restrict__ c) {
  int b = blockIdx.x >> 1;
  int h = ((blockIdx.x & 1) << 8) + threadIdx.x;
  __shared__ float hid[NH];
  for (int e = threadIdx.x; e < NH; e += 256) hid[e] = hidden[b * NH + e];
  __syncthreads();
  float acc = b_attn[h];
#pragma unroll 8
  for (int e = 0; e < NH; ++e) acc = fmaf(hid[e], W_attn[(size_t)e * NH + h], acc);
  c[b * NH + h] = acc;
}

// WeT[col][k] = fp16(W_e[k][col]) — transposed so B k-runs are contiguous.
__global__ __launch_bounds__(256) void prep_We_kernel(
    const float* __restrict__ W_attn, _Float16* __restrict__ WeT) {
  int k = blockIdx.x;  // 0..1023
  const float* src = W_attn + (size_t)(NH + k) * NH;
#pragma unroll
  for (int j = 0; j < 2; ++j) {
    int col = threadIdx.x + (j << 8);
    WeT[(size_t)col * NE + k] = (_Float16)src[col];
  }
}

// Fused  tanh(enc@W_e + c) . W_v  partials over a 256-col chunk.
// Tile 128(M)x256(N), BK=64, 512 threads / 8 waves (2M x 4N, wave 64x64).
// A staged as RAW FP32 via global_load_lds (no prep pass), cvt->fp16 in-reg
// after ds_read. B fp16 via global_load_lds. Both pre-swizzled-source /
// swizzled-read (rule #21). 2-phase: STAGE(t+1) -> compute(t) -> barrier.
__global__ __launch_bounds__(512) void score_kernel(
    const float* __restrict__ enc, const _Float16* __restrict__ WeT,
    const float* __restrict__ c, const float* __restrict__ Wv,
    float* __restrict__ spart) {
  __shared__ float Asm[2][128 * 64];      // fp32, 32 KB each, row stride 256 B
  __shared__ _Float16 Bsm[2][256 * 64];   // fp16, 32 KB each, col stride 128 B
  const int tid = threadIdx.x;
  const int lane = tid & 63;
  const int wid = tid >> 6;        // 0..7
  const int wr = wid >> 2;         // wave M-position (0,1)
  const int wc = wid & 3;          // wave N-position (0..3)
  const int r15 = lane & 15;
  // XCD-chunked mapping: xcd (id&7) gets 64 consecutive logical blocks so the
  // (mt, nc=0/1) pair shares its A-panel in that XCD's L2.
  const int id = blockIdx.x;                  // 0..511
  const int lb = ((id & 7) << 6) + (id >> 3);
  const int mt = lb >> 1;                     // 0..255 M-tile of 128 rows
  const int nc = lb & 1;                      // 256-col chunk
  const int b = mt >> 3;
  const int s0 = (mt & 7) << 7;
  const char* Abase = (const char*)(enc + ((size_t)b * NS + s0) * NE);  // rows of 4096 B
  const char* Wbase = (const char*)(WeT + ((size_t)(nc << 8)) * NE);    // cols of 2048 B

  f32x4 acc[4][4];
#pragma unroll
  for (int i = 0; i < 4; ++i)
#pragma unroll
    for (int j = 0; j < 4; ++j) acc[i][j] = (f32x4)0.f;

  // A LDS layout: byte d holds linear (row = d>>8, inrow = (d&255)^((row&15)<<4))
  // B LDS layout: byte d holds linear (col = d>>7, inrow = (d&127)^((col&7)<<4))
#define STAGE(KT, BUF)                                                           \
  {                                                                              \
    _Pragma("unroll") for (int i = 0; i < 4; ++i) {                              \
      int dbase = (i << 13) + (wid << 10);                                       \
      int d = dbase + (lane << 4);                                               \
      int row = d >> 8;                                                          \
      int sb = (d & 255) ^ ((row & 15) << 4);                                    \
      __builtin_amdgcn_global_load_lds(                                          \
          (const __attribute__((address_space(1))) uint32_t*)(Abase + (size_t)row * 4096 + ((KT) << 8) + sb), \
          (__attribute__((address_space(3))) uint32_t*)((char*)Asm[BUF] + dbase),\
          16, 0, 0);                                                             \
    }                                                                            \
    _Pragma("unroll") for (int i = 0; i < 4; ++i) {                              \
      int dbase = (i << 13) + (wid << 10);                                       \
      int d = dbase + (lane << 4);                                               \
      int col = d >> 7;                                                          \
      int sb = (d & 127) ^ ((col & 7) << 4);                                     \
      __builtin_amdgcn_global_load_lds(                                          \
          (const __attribute__((address_space(1))) uint32_t*)(Wbase + (size_t)col * 2048 + ((KT) << 7) + sb), \
          (__attribute__((address_space(3))) uint32_t*)((char*)Bsm[BUF] + dbase),\
          16, 0, 0);                                                             \
    }                                                                            \
  }

  STAGE(0, 0);
  __syncthreads();

  for (int kt = 0; kt < 16; ++kt) {
    const int cur = kt & 1, nxt = cur ^ 1;
    if (kt < 15) STAGE(kt + 1, nxt);   // issue-before-compute; barrier drains after
    // ---- compute on LDS[cur]: 2 k-slices of 32 ----
#pragma unroll
    for (int kk = 0; kk < 2; ++kk) {
      f16x8 af[4], bf[4];
#pragma unroll
      for (int mi = 0; mi < 4; ++mi) {
        int row = (wr << 6) + (mi << 4) + r15;
        int off1 = (row << 8) + (kk << 7) + ((lane >> 4) << 5);
        int x = (row & 15) << 4;
        f32x4 u = *(const f32x4*)((const char*)Asm[cur] + (off1 ^ x));
        f32x4 v = *(const f32x4*)((const char*)Asm[cur] + ((off1 + 16) ^ x));
        f16x8 h;
        h[0] = (_Float16)u[0]; h[1] = (_Float16)u[1];
        h[2] = (_Float16)u[2]; h[3] = (_Float16)u[3];
        h[4] = (_Float16)v[0]; h[5] = (_Float16)v[1];
        h[6] = (_Float16)v[2]; h[7] = (_Float16)v[3];
        af[mi] = h;
      }
#pragma unroll
      for (int nj = 0; nj < 4; ++nj) {
        int cb = (wc << 6) + (nj << 4) + r15;
        int off = (cb << 7) + (kk << 6) + ((lane >> 4) << 4);
        off ^= (cb & 7) << 4;
        bf[nj] = *(const f16x8*)((const char*)Bsm[cur] + off);
      }
#pragma unroll
      for (int mi = 0; mi < 4; ++mi)
#pragma unroll
        for (int nj = 0; nj < 4; ++nj)
          acc[mi][nj] = __builtin_amdgcn_mfma_f32_16x16x32_f16(af[mi], bf[nj], acc[mi][nj], 0, 0, 0);
    }
    __syncthreads();  // drains STAGE(t+1), protects both buffers
  }
#undef STAGE

  // ---- epilogue: fast-tanh + W_v dot over this wave's 64 cols ----
  float sr[4][4];
#pragma unroll
  for (int i = 0; i < 4; ++i)
#pragma unroll
    for (int r = 0; r < 4; ++r) sr[i][r] = 0.f;
#pragma unroll
  for (int nj = 0; nj < 4; ++nj) {
    int hcol = (nc << 8) + (wc << 6) + (nj << 4) + r15;
    float wvj = Wv[hcol];
    float cvj = c[b * NH + hcol];
#pragma unroll
    for (int mi = 0; mi < 4; ++mi)
#pragma unroll
      for (int r = 0; r < 4; ++r)
        sr[mi][r] += wvj * fast_tanh(acc[mi][nj][r] + cvj);
  }
  // reduce across the 16 col-lanes (fixed order -> deterministic)
#pragma unroll
  for (int off = 1; off < 16; off <<= 1)
#pragma unroll
    for (int mi = 0; mi < 4; ++mi)
#pragma unroll
      for (int r = 0; r < 4; ++r) sr[mi][r] += __shfl_xor(sr[mi][r], off, 64);
  if (r15 == 0) {
    float* dst = spart + (size_t)((nc << 2) + wc) * NB * NS + b * NS + s0 + (wr << 6);
#pragma unroll
    for (int mi = 0; mi < 4; ++mi)
#pragma unroll
      for (int r = 0; r < 4; ++r)
        dst[(mi << 4) + ((lane >> 4) << 2) + r] = sr[mi][r];
  }
}

// masked softmax over S per batch row; sums the 8 score partials first
__global__ __launch_bounds__(256) void softmax_kernel(
    const float* __restrict__ spart, const int* __restrict__ mask,
    float* __restrict__ attn) {
  int b = blockIdx.x, tid = threadIdx.x;
  __shared__ float red[8];
  float v[4];
  float mx = -INFINITY;
#pragma unroll
  for (int j = 0; j < 4; ++j) {
    int s = tid + (j << 8);
    float x = 0.f;
#pragma unroll
    for (int p = 0; p < 8; ++p) x += spart[(size_t)p * NB * NS + b * NS + s];
    v[j] = (mask[b * NS + s] == 0) ? NEGV : x;
    mx = fmaxf(mx, v[j]);
  }
#pragma unroll
  for (int off = 32; off >= 1; off >>= 1) mx = fmaxf(mx, __shfl_xor(mx, off, 64));
  if ((tid & 63) == 0) red[tid >> 6] = mx;
  __syncthreads();
  mx = fmaxf(fmaxf(red[0], red[1]), fmaxf(red[2], red[3]));
  float sum = 0.f;
#pragma unroll
  for (int j = 0; j < 4; ++j) {
    v[j] = __expf(v[j] - mx);
    sum += v[j];
  }
#pragma unroll
  for (int off = 32; off >= 1; off >>= 1) sum += __shfl_xor(sum, off, 64);
  __syncthreads();
  if ((tid & 63) == 0) red[4 + (tid >> 6)] = sum;
  __syncthreads();
  float inv = 1.f / (red[4] + red[5] + red[6] + red[7]);
#pragma unroll
  for (int j = 0; j < 4; ++j) attn[b * NS + tid + (j << 8)] = v[j] * inv;
}

// partial context over a 64-row S chunk (fp32 enc)
__global__ __launch_bounds__(256) void ctx_partial_kernel(
    const float* __restrict__ enc, const float* __restrict__ attn,
    float* __restrict__ partial) {
  int ch = blockIdx.x;  // 0..15
  int b = blockIdx.y;
  int tid = threadIdx.x;
  __shared__ float w[64];
  if (tid < 64) w[tid] = attn[b * NS + (ch << 6) + tid];
  __syncthreads();
  const float* encb = enc + ((size_t)b * NS + (ch << 6)) * NE;
  float4 acc = make_float4(0.f, 0.f, 0.f, 0.f);
  int e = tid << 2;
  for (int s = 0; s < 64; ++s) {
    float4 x = *(const float4*)(encb + (size_t)s * NE + e);
    float ws_ = w[s];
    acc.x = fmaf(ws_, x.x, acc.x);
    acc.y = fmaf(ws_, x.y, acc.y);
    acc.z = fmaf(ws_, x.z, acc.z);
    acc.w = fmaf(ws_, x.w, acc.w);
  }
  *(float4*)(partial + ((size_t)(b * 16 + ch)) * NE + e) = acc;
}

__global__ __launch_bounds__(256) void ctx_reduce_kernel(
    const float* __restrict__ partial, float* __restrict__ ctx) {
  int b = blockIdx.x;
  int e = threadIdx.x << 2;
  float4 acc = make_float4(0.f, 0.f, 0.f, 0.f);
  for (int ch = 0; ch < 16; ++ch) {
    float4 x = *(const float4*)(partial + ((size_t)(b * 16 + ch)) * NE + e);
    acc.x += x.x;
    acc.y += x.y;
    acc.z += x.z;
    acc.w += x.w;
  }
  *(float4*)(ctx + (size_t)b * NE + e) = acc;
}

extern "C" void kernel_launch(void* const* d_in, const int* in_sizes, int n_in,
                              void* d_out, int out_size, void* d_ws, size_t ws_size,
                              hipStream_t stream) {
  const float* hidden = (const float*)d_in[0];
  const float* enc = (const float*)d_in[1];
  const int* mask = (const int*)d_in[2];
  const float* W_attn = (const float*)d_in[3];
  const float* b_attn = (const float*)d_in[4];
  const float* W_v = (const float*)d_in[5];

  float* ctx = (float*)d_out;   // context: 32*1024
  float* attn = ctx + NB * NS;  // attn_w: 32*1024

  char* ws = (char*)d_ws;
  float* c = (float*)ws;                             // 64 KB
  float* spart = (float*)(ws + 65536);               // 8*32*1024 f32 = 1 MB
  float* partial = (float*)(ws + 65536 + 1048576);   // 32*16*1024 f32 = 2 MB
  _Float16* WeT = (_Float16*)(ws + 65536 + 1048576 + 2097152);  // 1 MB

  proj_h_kernel<<<64, 256, 0, stream>>>(hidden, W_attn, b_attn, c);
  prep_We_kernel<<<NE, 256, 0, stream>>>(W_attn, WeT);
  score_kernel<<<512, 512, 0, stream>>>(enc, WeT, c, W_v, spart);
  softmax_kernel<<<NB, 256, 0, stream>>>(spart, mask, attn);
  ctx_partial_kernel<<<dim3(16, NB), 256, 0, stream>>>(enc, attn, partial);
  ctx_reduce_kernel<<<NB, 256, 0, stream>>>(partial, ctx);
}

// Round 9
// 119.909 us; speedup vs baseline: 1.9757x; 1.0348x over previous
//
#include <hip/hip_runtime.h>
#include <hip/hip_bf16.h>
#include <math.h>

#define NB 32
#define NS 1024
#define NH 512
#define NE 1024   // 2H
#define NEGV -1e10f

typedef _Float16 f16x8 __attribute__((ext_vector_type(8)));
typedef _Float16 f16x4 __attribute__((ext_vector_type(4)));
typedef float f32x4 __attribute__((ext_vector_type(4)));

__device__ __forceinline__ float fast_tanh(float x) {
  float t = __expf(2.f * x);
  return (t - 1.f) * __builtin_amdgcn_rcpf(t + 1.f);
}

// c[b][h] = b_attn[h] + sum_e hidden[b][e] * W_h[e][h]   (fp32, tiny)
__global__ __launch_bounds__(256) void proj_h_kernel(
    const float* __restrict__ hidden, const float* __restrict__ W_attn,
    const float* __restrict__ b_attn, float* __restrict__ c) {
  int b = blockIdx.x >> 1;
  int h = ((blockIdx.x & 1) << 8) + threadIdx.x;
  __shared__ float hid[NH];
  for (int e = threadIdx.x; e < NH; e += 256) hid[e] = hidden[b * NH + e];
  __syncthreads();
  float acc = b_attn[h];
#pragma unroll 8
  for (int e = 0; e < NH; ++e) acc = fmaf(hid[e], W_attn[(size_t)e * NH + h], acc);
  c[b * NH + h] = acc;
}

// WeT[col][k] = fp16(W_e[k][col]) — transposed so B k-runs are contiguous.
__global__ __launch_bounds__(256) void prep_We_kernel(
    const float* __restrict__ W_attn, _Float16* __restrict__ WeT) {
  int k = blockIdx.x;  // 0..1023
  const float* src = W_attn + (size_t)(NH + k) * NH;
#pragma unroll
  for (int j = 0; j < 2; ++j) {
    int col = threadIdx.x + (j << 8);
    WeT[(size_t)col * NE + k] = (_Float16)src[col];
  }
}

// Fused  tanh(enc@W_e + c) . W_v  partials over a 256-col chunk.
// Tile 128(M)x256(N), BK=64, 512 threads / 8 waves (2M x 4N, wave 64x64).
// A raw fp32 via global_load_lds (cvt->fp16 after ds_read); B fp16 via
// global_load_lds. Counted-vmcnt + raw-barrier pipeline (m201/m218 lever):
// STAGE(t+1) stays in flight across barriers; only STAGE(t) is awaited.
__global__ __launch_bounds__(512) void score_kernel(
    const float* __restrict__ enc, const _Float16* __restrict__ WeT,
    const float* __restrict__ c, const float* __restrict__ Wv,
    float* __restrict__ spart) {
  __shared__ float Asm[2][128 * 64];      // fp32, 32 KB each, row stride 256 B
  __shared__ _Float16 Bsm[2][256 * 64];   // fp16, 32 KB each, col stride 128 B
  const int tid = threadIdx.x;
  const int lane = tid & 63;
  const int wid = tid >> 6;        // 0..7
  const int wr = wid >> 2;         // wave M-position (0,1)
  const int wc = wid & 3;          // wave N-position (0..3)
  const int r15 = lane & 15;
  const int id = blockIdx.x;                  // 0..511
  const int lb = ((id & 7) << 6) + (id >> 3); // XCD-chunked bijective map
  const int mt = lb >> 1;                     // M-tile of 128 rows
  const int nc = lb & 1;                      // 256-col chunk
  const int b = mt >> 3;
  const int s0 = (mt & 7) << 7;
  const char* Abase = (const char*)(enc + ((size_t)b * NS + s0) * NE);  // 4096 B rows
  const char* Wbase = (const char*)(WeT + ((size_t)(nc << 8)) * NE);    // 2048 B cols

  f32x4 acc[4][4];
#pragma unroll
  for (int i = 0; i < 4; ++i)
#pragma unroll
    for (int j = 0; j < 4; ++j) acc[i][j] = (f32x4)0.f;

  // A LDS: byte d holds linear (row=d>>8, inrow=(d&255)^((row&15)<<4))
  // B LDS: byte d holds linear (col=d>>7, inrow=(d&127)^((col&7)<<4))
  // 8 gload_lds per thread per STAGE -> vmcnt counts 8.
#define STAGE(KT, BUF)                                                           \
  {                                                                              \
    _Pragma("unroll") for (int i = 0; i < 4; ++i) {                              \
      int dbase = (i << 13) + (wid << 10);                                       \
      int d = dbase + (lane << 4);                                               \
      int row = d >> 8;                                                          \
      int sb = (d & 255) ^ ((row & 15) << 4);                                    \
      __builtin_amdgcn_global_load_lds(                                          \
          (const __attribute__((address_space(1))) uint32_t*)(Abase + (size_t)row * 4096 + ((KT) << 8) + sb), \
          (__attribute__((address_space(3))) uint32_t*)((char*)Asm[BUF] + dbase),\
          16, 0, 0);                                                             \
    }                                                                            \
    _Pragma("unroll") for (int i = 0; i < 4; ++i) {                              \
      int dbase = (i << 13) + (wid << 10);                                       \
      int d = dbase + (lane << 4);                                               \
      int col = d >> 7;                                                          \
      int sb = (d & 127) ^ ((col & 7) << 4);                                     \
      __builtin_amdgcn_global_load_lds(                                          \
          (const __attribute__((address_space(1))) uint32_t*)(Wbase + (size_t)col * 2048 + ((KT) << 7) + sb), \
          (__attribute__((address_space(3))) uint32_t*)((char*)Bsm[BUF] + dbase),\
          16, 0, 0);                                                             \
    }                                                                            \
  }

#define COMPUTE(CUR)                                                             \
  _Pragma("unroll") for (int kk = 0; kk < 2; ++kk) {                             \
    f16x8 af[4], bf[4];                                                          \
    _Pragma("unroll") for (int mi = 0; mi < 4; ++mi) {                           \
      int row = (wr << 6) + (mi << 4) + r15;                                     \
      int off1 = (row << 8) + (kk << 7) + ((lane >> 4) << 5);                    \
      int x = (row & 15) << 4;                                                   \
      f32x4 u = *(const f32x4*)((const char*)Asm[CUR] + (off1 ^ x));             \
      f32x4 v = *(const f32x4*)((const char*)Asm[CUR] + ((off1 + 16) ^ x));      \
      f16x8 h;                                                                   \
      h[0] = (_Float16)u[0]; h[1] = (_Float16)u[1];                              \
      h[2] = (_Float16)u[2]; h[3] = (_Float16)u[3];                              \
      h[4] = (_Float16)v[0]; h[5] = (_Float16)v[1];                              \
      h[6] = (_Float16)v[2]; h[7] = (_Float16)v[3];                              \
      af[mi] = h;                                                                \
    }                                                                            \
    _Pragma("unroll") for (int nj = 0; nj < 4; ++nj) {                           \
      int cb = (wc << 6) + (nj << 4) + r15;                                      \
      int off = (cb << 7) + (kk << 6) + ((lane >> 4) << 4);                      \
      off ^= (cb & 7) << 4;                                                      \
      bf[nj] = *(const f16x8*)((const char*)Bsm[CUR] + off);                     \
    }                                                                            \
    _Pragma("unroll") for (int mi = 0; mi < 4; ++mi)                             \
      _Pragma("unroll") for (int nj = 0; nj < 4; ++nj)                           \
        acc[mi][nj] = __builtin_amdgcn_mfma_f32_16x16x32_f16(af[mi], bf[nj],     \
                                                             acc[mi][nj], 0, 0, 0); \
  }

  // ---- prologue ----
  STAGE(0, 0);
  asm volatile("s_waitcnt vmcnt(0)" ::: "memory");
  __builtin_amdgcn_s_barrier();
  __builtin_amdgcn_sched_barrier(0);

  // ---- main loop: counted vmcnt keeps STAGE(t+1) in flight across barriers ----
  for (int kt = 0; kt < 15; ++kt) {
    const int cur = kt & 1, nxt = cur ^ 1;
    STAGE(kt + 1, nxt);
    // wait only for STAGE(cur) (8 newer loads of STAGE(kt+1) stay in flight)
    asm volatile("s_waitcnt vmcnt(8)" ::: "memory");
    __builtin_amdgcn_s_barrier();          // all waves' STAGE(cur) complete
    __builtin_amdgcn_sched_barrier(0);
    COMPUTE(cur);
    asm volatile("s_waitcnt lgkmcnt(0)" ::: "memory");  // reads of buf[cur] drained
    __builtin_amdgcn_s_barrier();          // safe for next iter's STAGE overwrite
    __builtin_amdgcn_sched_barrier(0);
  }
  // ---- tail: kt = 15 (buffer 1, staged in iter 14) ----
  asm volatile("s_waitcnt vmcnt(0)" ::: "memory");
  __builtin_amdgcn_s_barrier();
  __builtin_amdgcn_sched_barrier(0);
  COMPUTE(1);
#undef STAGE
#undef COMPUTE

  // ---- epilogue: fast-tanh + W_v dot over this wave's 64 cols ----
  float sr[4][4];
#pragma unroll
  for (int i = 0; i < 4; ++i)
#pragma unroll
    for (int r = 0; r < 4; ++r) sr[i][r] = 0.f;
#pragma unroll
  for (int nj = 0; nj < 4; ++nj) {
    int hcol = (nc << 8) + (wc << 6) + (nj << 4) + r15;
    float wvj = Wv[hcol];
    float cvj = c[b * NH + hcol];
#pragma unroll
    for (int mi = 0; mi < 4; ++mi)
#pragma unroll
      for (int r = 0; r < 4; ++r)
        sr[mi][r] += wvj * fast_tanh(acc[mi][nj][r] + cvj);
  }
  // reduce across the 16 col-lanes (fixed order -> deterministic)
#pragma unroll
  for (int off = 1; off < 16; off <<= 1)
#pragma unroll
    for (int mi = 0; mi < 4; ++mi)
#pragma unroll
      for (int r = 0; r < 4; ++r) sr[mi][r] += __shfl_xor(sr[mi][r], off, 64);
  if (r15 == 0) {
    float* dst = spart + (size_t)((nc << 2) + wc) * NB * NS + b * NS + s0 + (wr << 6);
#pragma unroll
    for (int mi = 0; mi < 4; ++mi)
#pragma unroll
      for (int r = 0; r < 4; ++r)
        dst[(mi << 4) + ((lane >> 4) << 2) + r] = sr[mi][r];
  }
}

// masked softmax over S per batch row; sums the 8 score partials first
__global__ __launch_bounds__(256) void softmax_kernel(
    const float* __restrict__ spart, const int* __restrict__ mask,
    float* __restrict__ attn) {
  int b = blockIdx.x, tid = threadIdx.x;
  __shared__ float red[8];
  float v[4];
  float mx = -INFINITY;
#pragma unroll
  for (int j = 0; j < 4; ++j) {
    int s = tid + (j << 8);
    float x = 0.f;
#pragma unroll
    for (int p = 0; p < 8; ++p) x += spart[(size_t)p * NB * NS + b * NS + s];
    v[j] = (mask[b * NS + s] == 0) ? NEGV : x;
    mx = fmaxf(mx, v[j]);
  }
#pragma unroll
  for (int off = 32; off >= 1; off >>= 1) mx = fmaxf(mx, __shfl_xor(mx, off, 64));
  if ((tid & 63) == 0) red[tid >> 6] = mx;
  __syncthreads();
  mx = fmaxf(fmaxf(red[0], red[1]), fmaxf(red[2], red[3]));
  float sum = 0.f;
#pragma unroll
  for (int j = 0; j < 4; ++j) {
    v[j] = __expf(v[j] - mx);
    sum += v[j];
  }
#pragma unroll
  for (int off = 32; off >= 1; off >>= 1) sum += __shfl_xor(sum, off, 64);
  __syncthreads();
  if ((tid & 63) == 0) red[4 + (tid >> 6)] = sum;
  __syncthreads();
  float inv = 1.f / (red[4] + red[5] + red[6] + red[7]);
#pragma unroll
  for (int j = 0; j < 4; ++j) attn[b * NS + tid + (j << 8)] = v[j] * inv;
}

// partial context over a 64-row S chunk (fp32 enc)
__global__ __launch_bounds__(256) void ctx_partial_kernel(
    const float* __restrict__ enc, const float* __restrict__ attn,
    float* __restrict__ partial) {
  int ch = blockIdx.x;  // 0..15
  int b = blockIdx.y;
  int tid = threadIdx.x;
  __shared__ float w[64];
  if (tid < 64) w[tid] = attn[b * NS + (ch << 6) + tid];
  __syncthreads();
  const float* encb = enc + ((size_t)b * NS + (ch << 6)) * NE;
  float4 acc = make_float4(0.f, 0.f, 0.f, 0.f);
  int e = tid << 2;
  for (int s = 0; s < 64; ++s) {
    float4 x = *(const float4*)(encb + (size_t)s * NE + e);
    float ws_ = w[s];
    acc.x = fmaf(ws_, x.x, acc.x);
    acc.y = fmaf(ws_, x.y, acc.y);
    acc.z = fmaf(ws_, x.z, acc.z);
    acc.w = fmaf(ws_, x.w, acc.w);
  }
  *(float4*)(partial + ((size_t)(b * 16 + ch)) * NE + e) = acc;
}

__global__ __launch_bounds__(256) void ctx_reduce_kernel(
    const float* __restrict__ partial, float* __restrict__ ctx) {
  int b = blockIdx.x;
  int e = threadIdx.x << 2;
  float4 acc = make_float4(0.f, 0.f, 0.f, 0.f);
  for (int ch = 0; ch < 16; ++ch) {
    float4 x = *(const float4*)(partial + ((size_t)(b * 16 + ch)) * NE + e);
    acc.x += x.x;
    acc.y += x.y;
    acc.z += x.z;
    acc.w += x.w;
  }
  *(float4*)(ctx + (size_t)b * NE + e) = acc;
}

extern "C" void kernel_launch(void* const* d_in, const int* in_sizes, int n_in,
                              void* d_out, int out_size, void* d_ws, size_t ws_size,
                              hipStream_t stream) {
  const float* hidden = (const float*)d_in[0];
  const float* enc = (const float*)d_in[1];
  const int* mask = (const int*)d_in[2];
  const float* W_attn = (const float*)d_in[3];
  const float* b_attn = (const float*)d_in[4];
  const float* W_v = (const float*)d_in[5];

  float* ctx = (float*)d_out;   // context: 32*1024
  float* attn = ctx + NB * NS;  // attn_w: 32*1024

  char* ws = (char*)d_ws;
  float* c = (float*)ws;                             // 64 KB
  float* spart = (float*)(ws + 65536);               // 8*32*1024 f32 = 1 MB
  float* partial = (float*)(ws + 65536 + 1048576);   // 32*16*1024 f32 = 2 MB
  _Float16* WeT = (_Float16*)(ws + 65536 + 1048576 + 2097152);  // 1 MB

  proj_h_kernel<<<64, 256, 0, stream>>>(hidden, W_attn, b_attn, c);
  prep_We_kernel<<<NE, 256, 0, stream>>>(W_attn, WeT);
  score_kernel<<<512, 512, 0, stream>>>(enc, WeT, c, W_v, spart);
  softmax_kernel<<<NB, 256, 0, stream>>>(spart, mask, attn);
  ctx_partial_kernel<<<dim3(16, NB), 256, 0, stream>>>(enc, attn, partial);
  ctx_reduce_kernel<<<NB, 256, 0, stream>>>(partial, ctx);
}

// Round 10
// 115.817 us; speedup vs baseline: 2.0455x; 1.0353x over previous
//
#include <hip/hip_runtime.h>
#include <hip/hip_bf16.h>
#include <math.h>

#define NB 32
#define NS 1024
#define NH 512
#define NE 1024   // 2H
#define NEGV -1e10f

typedef _Float16 f16x8 __attribute__((ext_vector_type(8)));
typedef _Float16 f16x4 __attribute__((ext_vector_type(4)));
typedef float f32x4 __attribute__((ext_vector_type(4)));

__device__ __forceinline__ float fast_tanh(float x) {
  float t = __expf(2.f * x);
  return (t - 1.f) * __builtin_amdgcn_rcpf(t + 1.f);
}

// c[b][h] = b_attn[h] + sum_e hidden[b][e] * W_h[e][h]   (fp32, tiny)
__global__ __launch_bounds__(256) void proj_h_kernel(
    const float* __restrict__ hidden, const float* __restrict__ W_attn,
    const float* __restrict__ b_attn, float* __restrict__ c) {
  int b = blockIdx.x >> 1;
  int h = ((blockIdx.x & 1) << 8) + threadIdx.x;
  __shared__ float hid[NH];
  for (int e = threadIdx.x; e < NH; e += 256) hid[e] = hidden[b * NH + e];
  __syncthreads();
  float acc = b_attn[h];
#pragma unroll 8
  for (int e = 0; e < NH; ++e) acc = fmaf(hid[e], W_attn[(size_t)e * NH + h], acc);
  c[b * NH + h] = acc;
}

// WeT[col][k] = fp16(W_e[k][col]) — transposed so B k-runs are contiguous.
__global__ __launch_bounds__(256) void prep_We_kernel(
    const float* __restrict__ W_attn, _Float16* __restrict__ WeT) {
  int k = blockIdx.x;  // 0..1023
  const float* src = W_attn + (size_t)(NH + k) * NH;
#pragma unroll
  for (int j = 0; j < 2; ++j) {
    int col = threadIdx.x + (j << 8);
    WeT[(size_t)col * NE + k] = (_Float16)src[col];
  }
}

// Fused  tanh(enc@W_e + c) . W_v  -> FINAL scores for 64 s-rows.
// BM=64, BN=512 (all cols -> A read ONCE), BK=32, 8 waves (wave 64x64).
// A raw fp32 + B fp16 via global_load_lds, pre-swizzled src / swizzled read.
// 2-phase, one barrier per K-step; 2 blocks/CU provide barrier-drain TLP.
__global__ __launch_bounds__(512, 4) void score_kernel(
    const float* __restrict__ enc, const _Float16* __restrict__ WeT,
    const float* __restrict__ c, const float* __restrict__ Wv,
    float* __restrict__ scores) {
  __shared__ float Asm[2][64 * 32];       // fp32, 8 KB each, row stride 128 B
  __shared__ _Float16 Bsm[2][512 * 32];   // fp16, 32 KB each, col stride 64 B
  const int tid = threadIdx.x;
  const int lane = tid & 63;
  const int wid = tid >> 6;        // 0..7 = wave's 64-col slice
  const int r15 = lane & 15;
  const int mt = blockIdx.x;       // 0..511
  const int b = mt >> 4;
  const int s0 = (mt & 15) << 6;
  const char* Abase = (const char*)(enc + ((size_t)b * NS + s0) * NE);  // 4096 B rows
  const char* Wbase = (const char*)WeT;                                 // 2048 B cols

  f32x4 acc[4][4];
#pragma unroll
  for (int i = 0; i < 4; ++i)
#pragma unroll
    for (int j = 0; j < 4; ++j) acc[i][j] = (f32x4)0.f;

  // A LDS: byte d <- linear src (row=d>>7, in-row 16B-unit ^ (row&7))
  // B LDS: byte d <- linear src (col=d>>6, in-col 16B-unit ^ ((col>>1)&3))
  // dest base is wave-uniform (HW adds lane*16); src carries the inverse swizzle.
#define STAGE(KT, BUF)                                                           \
  {                                                                              \
    {                                                                            \
      int d = tid << 4;                                                          \
      int row = d >> 7;                                                          \
      int sb = (d & 127) ^ ((row & 7) << 4);                                     \
      __builtin_amdgcn_global_load_lds(                                          \
          (const __attribute__((address_space(1))) uint32_t*)(Abase + (size_t)row * 4096 + ((KT) << 7) + sb), \
          (__attribute__((address_space(3))) uint32_t*)((char*)Asm[BUF] + (wid << 10)), \
          16, 0, 0);                                                             \
    }                                                                            \
    _Pragma("unroll") for (int i = 0; i < 4; ++i) {                              \
      int d = (i << 13) + (tid << 4);                                            \
      int col = d >> 6;                                                          \
      int sb = (d & 63) ^ (((col >> 1) & 3) << 4);                               \
      __builtin_amdgcn_global_load_lds(                                          \
          (const __attribute__((address_space(1))) uint32_t*)(Wbase + (size_t)col * 2048 + ((KT) << 6) + sb), \
          (__attribute__((address_space(3))) uint32_t*)((char*)Bsm[BUF] + (i << 13) + (wid << 10)), \
          16, 0, 0);                                                             \
    }                                                                            \
  }

#define COMPUTE(CUR)                                                             \
  {                                                                              \
    f16x8 af[4], bf[4];                                                          \
    _Pragma("unroll") for (int mi = 0; mi < 4; ++mi) {                           \
      int row = (mi << 4) + r15;                                                 \
      int off1 = (row << 7) + ((lane >> 4) << 5);                                \
      int x = (row & 7) << 4;                                                    \
      f32x4 u = *(const f32x4*)((const char*)Asm[CUR] + (off1 ^ x));             \
      f32x4 v = *(const f32x4*)((const char*)Asm[CUR] + ((off1 + 16) ^ x));      \
      f16x8 h;                                                                   \
      h[0] = (_Float16)u[0]; h[1] = (_Float16)u[1];                              \
      h[2] = (_Float16)u[2]; h[3] = (_Float16)u[3];                              \
      h[4] = (_Float16)v[0]; h[5] = (_Float16)v[1];                              \
      h[6] = (_Float16)v[2]; h[7] = (_Float16)v[3];                              \
      af[mi] = h;                                                                \
    }                                                                            \
    _Pragma("unroll") for (int nj = 0; nj < 4; ++nj) {                           \
      int col = (wid << 6) + (nj << 4) + r15;                                    \
      int off = (col << 6) + ((lane >> 4) << 4);                                 \
      off ^= ((col >> 1) & 3) << 4;                                              \
      bf[nj] = *(const f16x8*)((const char*)Bsm[CUR] + off);                     \
    }                                                                            \
    _Pragma("unroll") for (int mi = 0; mi < 4; ++mi)                             \
      _Pragma("unroll") for (int nj = 0; nj < 4; ++nj)                           \
        acc[mi][nj] = __builtin_amdgcn_mfma_f32_16x16x32_f16(af[mi], bf[nj],     \
                                                             acc[mi][nj], 0, 0, 0); \
  }

  STAGE(0, 0);
  __syncthreads();
  for (int kt = 0; kt < 32; ++kt) {
    const int cur = kt & 1, nxt = cur ^ 1;
    if (kt < 31) STAGE(kt + 1, nxt);  // in flight during compute; sync drains
    COMPUTE(cur);
    __syncthreads();
  }
#undef STAGE
#undef COMPUTE

  // ---- epilogue: fast-tanh + W_v dot over this wave's 64 cols ----
  float sr[4][4];
#pragma unroll
  for (int i = 0; i < 4; ++i)
#pragma unroll
    for (int r = 0; r < 4; ++r) sr[i][r] = 0.f;
#pragma unroll
  for (int nj = 0; nj < 4; ++nj) {
    int hcol = (wid << 6) + (nj << 4) + r15;
    float wvj = Wv[hcol];
    float cvj = c[b * NH + hcol];
#pragma unroll
    for (int mi = 0; mi < 4; ++mi)
#pragma unroll
      for (int r = 0; r < 4; ++r)
        sr[mi][r] += wvj * fast_tanh(acc[mi][nj][r] + cvj);
  }
  // reduce across the 16 col-lanes (fixed order -> deterministic)
#pragma unroll
  for (int off = 1; off < 16; off <<= 1)
#pragma unroll
    for (int mi = 0; mi < 4; ++mi)
#pragma unroll
      for (int r = 0; r < 4; ++r) sr[mi][r] += __shfl_xor(sr[mi][r], off, 64);
  // cross-wave reduce in LDS (reuse Asm; all compute done after final sync)
  float* red = (float*)Asm;  // 8 waves x 64 rows = 2 KB
  if (r15 == 0) {
#pragma unroll
    for (int mi = 0; mi < 4; ++mi)
#pragma unroll
      for (int r = 0; r < 4; ++r)
        red[(wid << 6) + (mi << 4) + ((lane >> 4) << 2) + r] = sr[mi][r];
  }
  __syncthreads();
  if (tid < 64) {
    float s = 0.f;
#pragma unroll
    for (int w = 0; w < 8; ++w) s += red[(w << 6) + tid];
    scores[b * NS + s0 + tid] = s;
  }
}

// masked softmax over S per batch row
__global__ __launch_bounds__(256) void softmax_kernel(
    const float* __restrict__ scores, const int* __restrict__ mask,
    float* __restrict__ attn) {
  int b = blockIdx.x, tid = threadIdx.x;
  __shared__ float red[8];
  float v[4];
  float mx = -INFINITY;
#pragma unroll
  for (int j = 0; j < 4; ++j) {
    int s = tid + (j << 8);
    float x = scores[b * NS + s];
    v[j] = (mask[b * NS + s] == 0) ? NEGV : x;
    mx = fmaxf(mx, v[j]);
  }
#pragma unroll
  for (int off = 32; off >= 1; off >>= 1) mx = fmaxf(mx, __shfl_xor(mx, off, 64));
  if ((tid & 63) == 0) red[tid >> 6] = mx;
  __syncthreads();
  mx = fmaxf(fmaxf(red[0], red[1]), fmaxf(red[2], red[3]));
  float sum = 0.f;
#pragma unroll
  for (int j = 0; j < 4; ++j) {
    v[j] = __expf(v[j] - mx);
    sum += v[j];
  }
#pragma unroll
  for (int off = 32; off >= 1; off >>= 1) sum += __shfl_xor(sum, off, 64);
  __syncthreads();
  if ((tid & 63) == 0) red[4 + (tid >> 6)] = sum;
  __syncthreads();
  float inv = 1.f / (red[4] + red[5] + red[6] + red[7]);
#pragma unroll
  for (int j = 0; j < 4; ++j) attn[b * NS + tid + (j << 8)] = v[j] * inv;
}

// partial context over a 64-row S chunk (fp32 enc)
__global__ __launch_bounds__(256) void ctx_partial_kernel(
    const float* __restrict__ enc, const float* __restrict__ attn,
    float* __restrict__ partial) {
  int ch = blockIdx.x;  // 0..15
  int b = blockIdx.y;
  int tid = threadIdx.x;
  __shared__ float w[64];
  if (tid < 64) w[tid] = attn[b * NS + (ch << 6) + tid];
  __syncthreads();
  const float* encb = enc + ((size_t)b * NS + (ch << 6)) * NE;
  float4 acc = make_float4(0.f, 0.f, 0.f, 0.f);
  int e = tid << 2;
  for (int s = 0; s < 64; ++s) {
    float4 x = *(const float4*)(encb + (size_t)s * NE + e);
    float ws_ = w[s];
    acc.x = fmaf(ws_, x.x, acc.x);
    acc.y = fmaf(ws_, x.y, acc.y);
    acc.z = fmaf(ws_, x.z, acc.z);
    acc.w = fmaf(ws_, x.w, acc.w);
  }
  *(float4*)(partial + ((size_t)(b * 16 + ch)) * NE + e) = acc;
}

__global__ __launch_bounds__(256) void ctx_reduce_kernel(
    const float* __restrict__ partial, float* __restrict__ ctx) {
  int b = blockIdx.x;
  int e = threadIdx.x << 2;
  float4 acc = make_float4(0.f, 0.f, 0.f, 0.f);
  for (int ch = 0; ch < 16; ++ch) {
    float4 x = *(const float4*)(partial + ((size_t)(b * 16 + ch)) * NE + e);
    acc.x += x.x;
    acc.y += x.y;
    acc.z += x.z;
    acc.w += x.w;
  }
  *(float4*)(ctx + (size_t)b * NE + e) = acc;
}

extern "C" void kernel_launch(void* const* d_in, const int* in_sizes, int n_in,
                              void* d_out, int out_size, void* d_ws, size_t ws_size,
                              hipStream_t stream) {
  const float* hidden = (const float*)d_in[0];
  const float* enc = (const float*)d_in[1];
  const int* mask = (const int*)d_in[2];
  const float* W_attn = (const float*)d_in[3];
  const float* b_attn = (const float*)d_in[4];
  const float* W_v = (const float*)d_in[5];

  float* ctx = (float*)d_out;   // context: 32*1024
  float* attn = ctx + NB * NS;  // attn_w: 32*1024

  char* ws = (char*)d_ws;
  float* c = (float*)ws;                              // 64 KB
  float* scores = (float*)(ws + 65536);               // 32*1024 f32 = 128 KB
  float* partial = (float*)(ws + 65536 + 131072);     // 32*16*1024 f32 = 2 MB
  _Float16* WeT = (_Float16*)(ws + 65536 + 131072 + 2097152);  // 1 MB

  proj_h_kernel<<<64, 256, 0, stream>>>(hidden, W_attn, b_attn, c);
  prep_We_kernel<<<NE, 256, 0, stream>>>(W_attn, WeT);
  score_kernel<<<512, 512, 0, stream>>>(enc, WeT, c, W_v, scores);
  softmax_kernel<<<NB, 256, 0, stream>>>(scores, mask, attn);
  ctx_partial_kernel<<<dim3(16, NB), 256, 0, stream>>>(enc, attn, partial);
  ctx_reduce_kernel<<<NB, 256, 0, stream>>>(partial, ctx);
}